// Round 15
// baseline (464.705 us; speedup 1.0000x reference)
//
#include <hip/hip_runtime.h>
#include <hip/hip_bf16.h>
#include <hip/hip_cooperative_groups.h>
#include <math.h>

namespace cg = cooperative_groups;

#define NN 50000
#define NE 800000
#define NBUK 391      // ceil(NN/128)
#define BNODES 128
#define CSRB 196      // csr grid blocks (196*256 = 50176 >= NN; 196*4096 >= NE)

typedef __attribute__((ext_vector_type(8))) short bf16x8;
typedef __attribute__((ext_vector_type(4))) float f32x4;
typedef __attribute__((ext_vector_type(8))) unsigned short ushort8v;

__device__ __forceinline__ ushort f2bf(float v) {
  __hip_bfloat16 h = __float2bfloat16(v);
  return *(ushort*)&h;
}
__device__ __forceinline__ float bf2f(ushort u) {
  return __uint_as_float(((unsigned int)u) << 16);
}

// -------- pack W (both layers) into MFMA B-frag bf16 layout ---------------
// t<4096 -> layer1 into Bp1, else layer2 into Bp2.
__global__ void pack_w_both(const float* __restrict__ Wl1, const float* __restrict__ Wr1,
                            const float* __restrict__ Wl2, const float* __restrict__ Wr2,
                            ushort* __restrict__ Bp1, ushort* __restrict__ Bp2) {
  int t = blockIdx.x * 256 + threadIdx.x;   // 0..8191
  if (t >= 8192) return;
  int layer = t >> 12;
  int tt = t & 4095;
  int hi = tt & 3;
  int col = (tt >> 2) & 255;
  int kt = tt >> 10;
  const float* Wl = layer ? Wl2 : Wl1;
  const float* Wr = layer ? Wr2 : Wr1;
  ushort* Bp = layer ? Bp2 : Bp1;
  const float* W = (col < 128) ? (Wl + col) : (Wr + (col - 128));
  ushort4 u0, u1;
  int k0 = kt * 32 + hi * 8;
  u0.x = f2bf(W[(k0 + 0) * 128]); u0.y = f2bf(W[(k0 + 1) * 128]);
  u0.z = f2bf(W[(k0 + 2) * 128]); u0.w = f2bf(W[(k0 + 3) * 128]);
  u1.x = f2bf(W[(k0 + 4) * 128]); u1.y = f2bf(W[(k0 + 5) * 128]);
  u1.z = f2bf(W[(k0 + 6) * 128]); u1.w = f2bf(W[(k0 + 7) * 128]);
  *(ushort4*)&Bp[tt * 8] = u0;
  *(ushort4*)&Bp[tt * 8 + 4] = u1;
}

// -------- MFMA dual GEMM: [Xl|Xr](bf16) = A @ [Wl|Wr] + [bl|br] -----------
template <int AF32>
__global__ __launch_bounds__(256) void gemm_mfma(
    const void* __restrict__ Aptr, const ushort* __restrict__ Bpack,
    const float* __restrict__ bl, const float* __restrict__ br,
    ushort* __restrict__ Xl, ushort* __restrict__ Xr, int n) {
  __shared__ ushort tile[64][264];   // row stride 528B (16B-aligned)
  const int tid = threadIdx.x;
  const int wv = tid >> 6;
  const int l = tid & 63;
  const int lr = l & 15;
  const int hi = l >> 4;
  const int r0 = blockIdx.x * 64;

  f32x4 acc[4][4];
#pragma unroll
  for (int mi = 0; mi < 4; ++mi)
#pragma unroll
    for (int nj = 0; nj < 4; ++nj) acc[mi][nj] = (f32x4)0.f;

#pragma unroll
  for (int kt = 0; kt < 4; ++kt) {
    bf16x8 b[4], a[4];
#pragma unroll
    for (int nj = 0; nj < 4; ++nj) {
      int col = wv * 64 + nj * 16 + lr;
      b[nj] = *(const bf16x8*)&Bpack[((kt * 256 + col) * 4 + hi) * 8];
    }
#pragma unroll
    for (int mi = 0; mi < 4; ++mi) {
      int row = r0 + mi * 16 + lr;
      row = row < n ? row : n - 1;     // clamp tail reads (stores guarded)
      if (AF32) {
        const float* Af = (const float*)Aptr;
        float4 f0 = *(const float4*)&Af[row * 128 + kt * 32 + hi * 8];
        float4 f1 = *(const float4*)&Af[row * 128 + kt * 32 + hi * 8 + 4];
        bf16x8 av;
        av[0] = (short)f2bf(f0.x); av[1] = (short)f2bf(f0.y);
        av[2] = (short)f2bf(f0.z); av[3] = (short)f2bf(f0.w);
        av[4] = (short)f2bf(f1.x); av[5] = (short)f2bf(f1.y);
        av[6] = (short)f2bf(f1.z); av[7] = (short)f2bf(f1.w);
        a[mi] = av;
      } else {
        const ushort* Ab = (const ushort*)Aptr;
        a[mi] = *(const bf16x8*)&Ab[row * 128 + kt * 32 + hi * 8];
      }
    }
#pragma unroll
    for (int mi = 0; mi < 4; ++mi)
#pragma unroll
      for (int nj = 0; nj < 4; ++nj)
        acc[mi][nj] = __builtin_amdgcn_mfma_f32_16x16x32_bf16(a[mi], b[nj], acc[mi][nj], 0, 0, 0);
  }

  // acc -> LDS (bias added)
#pragma unroll
  for (int nj = 0; nj < 4; ++nj) {
    int col = wv * 64 + nj * 16 + lr;
    float bb = (col < 128) ? bl[col] : br[col - 128];
#pragma unroll
    for (int mi = 0; mi < 4; ++mi)
#pragma unroll
      for (int v = 0; v < 4; ++v)
        tile[mi * 16 + hi * 4 + v][col] = f2bf(acc[mi][nj][v] + bb);
  }
  __syncthreads();

  // coalesced store: 8 chunks of 16B per thread
#pragma unroll
  for (int j = 0; j < 8; ++j) {
    int c = j * 256 + tid;          // 0..2047
    int rl = c >> 5;                // local row
    int colc = (c & 31) * 8;        // col chunk start
    int row = r0 + rl;
    if (row < n) {
      ushort* dstp = (colc < 128) ? &Xl[row * 128 + colc] : &Xr[row * 128 + (colc - 128)];
      *(ushort8v*)dstp = *(const ushort8v*)&tile[rl][colc];
    }
  }
}

// ---------------- CSR build: single cooperative kernel --------------------
// phases: zero deg -> hist -> block scan -> top scan -> finalize/cursors ->
// bucket scatter (pairs packed: dlocal<<17 | src) -> per-bucket fine sort.
__global__ __launch_bounds__(256) void csr_build(
    const int* __restrict__ src, const int* __restrict__ dst,
    int* __restrict__ deg, int* __restrict__ rowptr, int* __restrict__ bsum,
    int* __restrict__ boff, int* __restrict__ bcur,
    unsigned int* __restrict__ pairs, int* __restrict__ ssort) {
  cg::grid_group grid = cg::this_grid();
  const int t = threadIdx.x;
  const int bid = blockIdx.x;
  const int gid = bid * 256 + t;
  __shared__ int wsum[4];
  __shared__ int cnt[NBUK];
  __shared__ int base[NBUK];
  __shared__ int cur[BNODES];

  // phase 0: zero deg
  if (gid < NN) deg[gid] = 0;
  grid.sync();

  // phase 1: histogram
  {
    const int e0 = bid * 4096;
#pragma unroll
    for (int j = 0; j < 16; ++j) {
      int e = e0 + j * 256 + t;
      if (e < NE) atomicAdd(&deg[dst[e]], 1);
    }
  }
  grid.sync();

  // phase 2: block-local exclusive scan (block b covers [b*256, b*256+256))
  {
    int v = (gid < NN) ? deg[gid] : 0;
    int lane = t & 63, wid = t >> 6;
    int incl = v;
#pragma unroll
    for (int off = 1; off < 64; off <<= 1) {
      int u = __shfl_up(incl, off);
      if (lane >= off) incl += u;
    }
    if (lane == 63) wsum[wid] = incl;
    __syncthreads();
    int wo = 0;
    for (int w = 0; w < wid; w++) wo += wsum[w];
    if (gid < NN) rowptr[gid] = wo + incl - v;
    if (t == 255) bsum[bid] = wo + incl;
  }
  grid.sync();

  // phase 3: block 0 scans bsum[0..CSRB)
  if (bid == 0) {
    int v = (t < CSRB) ? bsum[t] : 0;
    int lane = t & 63, wid = t >> 6;
    int incl = v;
#pragma unroll
    for (int off = 1; off < 64; off <<= 1) {
      int u = __shfl_up(incl, off);
      if (lane >= off) incl += u;
    }
    __syncthreads();           // wsum reuse from phase 2
    if (lane == 63) wsum[wid] = incl;
    __syncthreads();
    int wo = 0;
    for (int w = 0; w < wid; w++) wo += wsum[w];
    boff[t] = wo + incl - v;
  }
  grid.sync();

  // phase 4: finalize rowptr + init bucket cursors
  {
    int i = gid;
    if (i < NN) {
      int v = rowptr[i] + boff[i >> 8];
      rowptr[i] = v;
      if ((i & 127) == 0) bcur[i >> 7] = v;
    } else if (i == NN) {
      rowptr[NN] = NE;
    }
  }
  grid.sync();

  // phase 5: coarse bucket scatter
  {
    for (int i = t; i < NBUK; i += 256) cnt[i] = 0;
    __syncthreads();
    const int e0 = bid * 4096;
#pragma unroll
    for (int j = 0; j < 16; ++j) {
      int e = e0 + j * 256 + t;
      if (e < NE) atomicAdd(&cnt[dst[e] >> 7], 1);
    }
    __syncthreads();
    for (int i = t; i < NBUK; i += 256) {
      int c = cnt[i];
      base[i] = c ? atomicAdd(&bcur[i], c) : 0;
      cnt[i] = 0;
    }
    __syncthreads();
#pragma unroll
    for (int j = 0; j < 16; ++j) {
      int e = e0 + j * 256 + t;
      if (e < NE) {
        int d = dst[e];
        int b = d >> 7;
        int r = atomicAdd(&cnt[b], 1);
        pairs[base[b] + r] = ((unsigned int)(d & 127) << 17) | (unsigned int)src[e];
      }
    }
  }
  grid.sync();

  // phase 6: per-bucket fine sort (each block loops over buckets)
  for (int b = bid; b < NBUK; b += CSRB) {
    int n0 = b * BNODES;
    int n1 = min(n0 + BNODES, NN);
    if (t < BNODES && n0 + t < NN) cur[t] = rowptr[n0 + t];
    __syncthreads();
    const int e0 = rowptr[n0];
    const int e1 = rowptr[n1];
    for (int e = e0 + t; e < e1; e += 256) {
      unsigned int p = pairs[e];
      int pos = atomicAdd(&cur[p >> 17], 1);
      ssort[pos] = (int)(p & 0x1FFFF);
    }
    __syncthreads();           // protect cur reuse across bucket iterations
  }
}

// ------- fused: logits + segment-softmax + aggregate + bias + ELU ---------
// 16 lanes/node x 8 channels/lane. Branchless logit, log2e folded.
template <int MODE>
__global__ __launch_bounds__(256) void gat_aggregate(
    const ushort* __restrict__ Xl, const ushort* __restrict__ Xr,
    const float* __restrict__ att, const int* __restrict__ ssort,
    const int* __restrict__ rowptr, const float* __restrict__ bias,
    ushort* __restrict__ outb,
    const float* __restrict__ Wl3, const float* __restrict__ Wr3,
    const float* __restrict__ bl3, const float* __restrict__ br3,
    float* __restrict__ xl3, float* __restrict__ xr3) {
  int slot = threadIdx.x >> 4;        // 16 nodes per block
  int l = threadIdx.x & 15;           // lane in node; head = l>>2
  int n = blockIdx.x * 16 + slot;
  if (n >= NN) return;
  int s0 = rowptr[n], s1 = rowptr[n + 1];
  ushort8v xru = *(const ushort8v*)&Xr[n * 128 + l * 8];
  const float L2E = 1.44269504f;
  float xr[8], a6[8], a4[8];
#pragma unroll
  for (int c = 0; c < 8; ++c) {
    xr[c] = bf2f(xru[c]);
    float a = att[l * 8 + c];
    a6[c] = 0.6f * L2E * a;
    a4[c] = 0.4f * L2E * a;
  }
  float den = 0.f;
  float A0[8], A1[8];
#pragma unroll
  for (int c = 0; c < 8; ++c) { A0[c] = 0.f; A1[c] = 0.f; }

  int i = s0;
  for (; i + 4 <= s1; i += 4) {
    int sa = ssort[i], sb = ssort[i + 1], sc = ssort[i + 2], sd = ssort[i + 3];
    ushort8v ua = *(const ushort8v*)&Xl[sa * 128 + l * 8];
    ushort8v ub = *(const ushort8v*)&Xl[sb * 128 + l * 8];
    ushort8v uc = *(const ushort8v*)&Xl[sc * 128 + l * 8];
    ushort8v ud = *(const ushort8v*)&Xl[sd * 128 + l * 8];
    float xa[8], xb[8], xc[8], xd[8];
    float pa = 0.f, pb = 0.f, pc = 0.f, pd = 0.f;
#pragma unroll
    for (int c = 0; c < 8; ++c) {
      float va;
      xa[c] = bf2f(ua[c]); va = xa[c] + xr[c];
      pa = fmaf(a6[c], va, pa); pa = fmaf(a4[c], fabsf(va), pa);
      xb[c] = bf2f(ub[c]); va = xb[c] + xr[c];
      pb = fmaf(a6[c], va, pb); pb = fmaf(a4[c], fabsf(va), pb);
      xc[c] = bf2f(uc[c]); va = xc[c] + xr[c];
      pc = fmaf(a6[c], va, pc); pc = fmaf(a4[c], fabsf(va), pc);
      xd[c] = bf2f(ud[c]); va = xd[c] + xr[c];
      pd = fmaf(a6[c], va, pd); pd = fmaf(a4[c], fabsf(va), pd);
    }
    pa += __shfl_xor(pa, 1); pa += __shfl_xor(pa, 2);
    pb += __shfl_xor(pb, 1); pb += __shfl_xor(pb, 2);
    pc += __shfl_xor(pc, 1); pc += __shfl_xor(pc, 2);
    pd += __shfl_xor(pd, 1); pd += __shfl_xor(pd, 2);
    float wa = exp2f(fminf(pa, 43.f));
    float wb = exp2f(fminf(pb, 43.f));
    float wc = exp2f(fminf(pc, 43.f));
    float wd = exp2f(fminf(pd, 43.f));
    den += (wa + wb) + (wc + wd);
#pragma unroll
    for (int c = 0; c < 8; ++c) {
      A0[c] = fmaf(wa, xa[c], A0[c]); A1[c] = fmaf(wb, xb[c], A1[c]);
      A0[c] = fmaf(wc, xc[c], A0[c]); A1[c] = fmaf(wd, xd[c], A1[c]);
    }
  }
  for (; i < s1; ++i) {
    int sa = ssort[i];
    ushort8v ua = *(const ushort8v*)&Xl[sa * 128 + l * 8];
    float xa[8], pa = 0.f;
#pragma unroll
    for (int c = 0; c < 8; ++c) {
      xa[c] = bf2f(ua[c]);
      float va = xa[c] + xr[c];
      pa = fmaf(a6[c], va, pa); pa = fmaf(a4[c], fabsf(va), pa);
    }
    pa += __shfl_xor(pa, 1); pa += __shfl_xor(pa, 2);
    float wa = exp2f(fminf(pa, 43.f));
    den += wa;
#pragma unroll
    for (int c = 0; c < 8; ++c) A0[c] = fmaf(wa, xa[c], A0[c]);
  }
  float inv = 1.f / (den + 1e-16f);
  float o[8];
#pragma unroll
  for (int c = 0; c < 8; ++c) {
    o[c] = (A0[c] + A1[c]) * inv + bias[l * 8 + c];
    o[c] = o[c] > 0.f ? o[c] : __expf(o[c]) - 1.f;
  }
  if (MODE == 0) {
    ushort8v ub;
#pragma unroll
    for (int c = 0; c < 8; ++c) ub[c] = f2bf(o[c]);
    *(ushort8v*)&outb[n * 128 + l * 8] = ub;
  } else {
    float sl = 0.f, sr = 0.f;
#pragma unroll
    for (int c = 0; c < 8; ++c) {
      sl = fmaf(o[c], Wl3[l * 8 + c], sl);
      sr = fmaf(o[c], Wr3[l * 8 + c], sr);
    }
#pragma unroll
    for (int off = 1; off <= 8; off <<= 1) {
      sl += __shfl_xor(sl, off);
      sr += __shfl_xor(sr, off);
    }
    if (l == 0) {
      xl3[n] = sl + bl3[0];
      xr3[n] = sr + br3[0];
    }
  }
}

// fused layer-3 edge phase: per-node wave, no-max softmax, wave merge
__global__ __launch_bounds__(256) void aggregate3_fused(
    const float* __restrict__ xl3, const float* __restrict__ xr3,
    const float* __restrict__ att, const int* __restrict__ ssort,
    const int* __restrict__ rowptr, const float* __restrict__ bias,
    float* __restrict__ out, int nn) {
  int wid = threadIdx.x >> 6, lane = threadIdx.x & 63;
  int n = blockIdx.x * 4 + wid;
  if (n >= nn) return;
  int s0 = rowptr[n], s1 = rowptr[n + 1];
  float xr = xr3[n];
  const float L2E = 1.44269504f;
  float s6 = 0.6f * L2E * att[0];
  float s4 = 0.4f * L2E * att[0];
  float den = 0.f, acc = 0.f;
  for (int i = s0 + lane; i < s1; i += 64) {
    float xl = xl3[ssort[i]];
    float v = xl + xr;
    float p = fmaf(s6, v, s4 * fabsf(v));
    float w = exp2f(fminf(p, 43.f));
    den += w;
    acc += w * xl;
  }
#pragma unroll
  for (int off = 32; off; off >>= 1) {
    den += __shfl_xor(den, off);
    acc += __shfl_xor(acc, off);
  }
  if (lane == 0) {
    float o = acc / (den + 1e-16f) + bias[0];
    out[n] = 1.f / (1.f + __expf(-o));
  }
}

extern "C" void kernel_launch(void* const* d_in, const int* in_sizes, int n_in,
                              void* d_out, int out_size, void* d_ws, size_t ws_size,
                              hipStream_t stream) {
  const float* x = (const float*)d_in[0];
  const int* ei = (const int*)d_in[1];
  const int* src = ei;
  const int* dst = ei + NE;
  const float* W_l1 = (const float*)d_in[2];
  const float* b_l1 = (const float*)d_in[3];
  const float* W_r1 = (const float*)d_in[4];
  const float* b_r1 = (const float*)d_in[5];
  const float* att1 = (const float*)d_in[6];
  const float* bias1 = (const float*)d_in[7];
  const float* W_l2 = (const float*)d_in[8];
  const float* b_l2 = (const float*)d_in[9];
  const float* W_r2 = (const float*)d_in[10];
  const float* b_r2 = (const float*)d_in[11];
  const float* att2 = (const float*)d_in[12];
  const float* bias2 = (const float*)d_in[13];
  const float* W_l3 = (const float*)d_in[14];
  const float* b_l3 = (const float*)d_in[15];
  const float* W_r3 = (const float*)d_in[16];
  const float* b_r3 = (const float*)d_in[17];
  const float* att3 = (const float*)d_in[18];
  const float* bias3 = (const float*)d_in[19];
  float* out = (float*)d_out;

  ushort* xbb = (ushort*)d_ws;           // NN*128 bf16 (layer-2 gemm A input)
  ushort* xl_b = xbb + NN * 128;         // NN*128 bf16
  ushort* xr_b = xl_b + NN * 128;        // NN*128 bf16
  ushort* bpack1 = xr_b + NN * 128;      // 32768 bf16
  ushort* bpack2 = bpack1 + 32768;       // 32768 bf16
  int* deg = (int*)(bpack2 + 32768);     // NN
  int* rowptr = deg + NN;                // NN+1
  int* bcur = rowptr + NN + 1;           // NBUK
  int* bsum = bcur + NBUK;               // 256
  int* boff = bsum + 256;                // 256
  int* ssort = boff + 256;               // NE
  unsigned int* pairs = (unsigned int*)(ssort + NE);  // NE packed
  float* xl3 = (float*)(pairs + NE);     // NN
  float* xr3 = xl3 + NN;                 // NN

  const int NB_G = (NN + 63) / 64;       // 782
  const int NB_A = (NN + 15) / 16;       // 3125
  const int NB_W4 = (NN + 3) / 4;        // 12500

  // ---- CSR build: one cooperative kernel ----
  {
    void* args[] = {(void*)&src, (void*)&dst, (void*)&deg, (void*)&rowptr,
                    (void*)&bsum, (void*)&boff, (void*)&bcur, (void*)&pairs,
                    (void*)&ssort};
    hipLaunchCooperativeKernel((void*)csr_build, dim3(CSRB), dim3(256), args, 0, stream);
  }

  // ---- weight packing (both layers, one launch) ----
  pack_w_both<<<32, 256, 0, stream>>>(W_l1, W_r1, W_l2, W_r2, bpack1, bpack2);

  // ---- layer 1 (A = fp32 x, converted in-register) ----
  gemm_mfma<1><<<NB_G, 256, 0, stream>>>(x, bpack1, b_l1, b_r1, xl_b, xr_b, NN);
  gat_aggregate<0><<<NB_A, 256, 0, stream>>>(xl_b, xr_b, att1, ssort, rowptr, bias1,
                                             xbb, nullptr, nullptr, nullptr, nullptr,
                                             nullptr, nullptr);

  // ---- layer 2 (+ fused layer-3 GEMV epilogue) ----
  gemm_mfma<0><<<NB_G, 256, 0, stream>>>(xbb, bpack2, b_l2, b_r2, xl_b, xr_b, NN);
  gat_aggregate<1><<<NB_A, 256, 0, stream>>>(xl_b, xr_b, att2, ssort, rowptr, bias2,
                                             nullptr, W_l3, W_r3, b_l3, b_r3,
                                             xl3, xr3);

  // ---- layer 3 edge phase ----
  aggregate3_fused<<<NB_W4, 256, 0, stream>>>(xl3, xr3, att3, ssort, rowptr, bias3, out, NN);
}

// Round 16
// 303.473 us; speedup vs baseline: 1.5313x; 1.5313x over previous
//
#include <hip/hip_runtime.h>
#include <hip/hip_bf16.h>
#include <math.h>

#define NN 50000
#define NE 800000
#define NBUK 391      // ceil(NN/128)
#define BNODES 128

typedef __attribute__((ext_vector_type(8))) short bf16x8;
typedef __attribute__((ext_vector_type(4))) float f32x4;
typedef __attribute__((ext_vector_type(8))) unsigned short ushort8v;

__device__ __forceinline__ ushort f2bf(float v) {
  __hip_bfloat16 h = __float2bfloat16(v);
  return *(ushort*)&h;
}
__device__ __forceinline__ float bf2f(ushort u) {
  return __uint_as_float(((unsigned int)u) << 16);
}

// -------- pack W (both layers) into MFMA B-frag bf16 layout ---------------
__global__ void pack_w_both(const float* __restrict__ Wl1, const float* __restrict__ Wr1,
                            const float* __restrict__ Wl2, const float* __restrict__ Wr2,
                            ushort* __restrict__ Bp1, ushort* __restrict__ Bp2) {
  int t = blockIdx.x * 256 + threadIdx.x;   // 0..8191
  if (t >= 8192) return;
  int layer = t >> 12;
  int tt = t & 4095;
  int hi = tt & 3;
  int col = (tt >> 2) & 255;
  int kt = tt >> 10;
  const float* Wl = layer ? Wl2 : Wl1;
  const float* Wr = layer ? Wr2 : Wr1;
  ushort* Bp = layer ? Bp2 : Bp1;
  const float* W = (col < 128) ? (Wl + col) : (Wr + (col - 128));
  ushort4 u0, u1;
  int k0 = kt * 32 + hi * 8;
  u0.x = f2bf(W[(k0 + 0) * 128]); u0.y = f2bf(W[(k0 + 1) * 128]);
  u0.z = f2bf(W[(k0 + 2) * 128]); u0.w = f2bf(W[(k0 + 3) * 128]);
  u1.x = f2bf(W[(k0 + 4) * 128]); u1.y = f2bf(W[(k0 + 5) * 128]);
  u1.z = f2bf(W[(k0 + 6) * 128]); u1.w = f2bf(W[(k0 + 7) * 128]);
  *(ushort4*)&Bp[tt * 8] = u0;
  *(ushort4*)&Bp[tt * 8 + 4] = u1;
}

// -------- MFMA dual GEMM: [Xl|Xr](bf16) = A @ [Wl|Wr] + [bl|br] -----------
template <int AF32>
__global__ __launch_bounds__(256) void gemm_mfma(
    const void* __restrict__ Aptr, const ushort* __restrict__ Bpack,
    const float* __restrict__ bl, const float* __restrict__ br,
    ushort* __restrict__ Xl, ushort* __restrict__ Xr, int n) {
  __shared__ ushort tile[64][264];   // row stride 528B (16B-aligned)
  const int tid = threadIdx.x;
  const int wv = tid >> 6;
  const int l = tid & 63;
  const int lr = l & 15;
  const int hi = l >> 4;
  const int r0 = blockIdx.x * 64;

  f32x4 acc[4][4];
#pragma unroll
  for (int mi = 0; mi < 4; ++mi)
#pragma unroll
    for (int nj = 0; nj < 4; ++nj) acc[mi][nj] = (f32x4)0.f;

#pragma unroll
  for (int kt = 0; kt < 4; ++kt) {
    bf16x8 b[4], a[4];
#pragma unroll
    for (int nj = 0; nj < 4; ++nj) {
      int col = wv * 64 + nj * 16 + lr;
      b[nj] = *(const bf16x8*)&Bpack[((kt * 256 + col) * 4 + hi) * 8];
    }
#pragma unroll
    for (int mi = 0; mi < 4; ++mi) {
      int row = r0 + mi * 16 + lr;
      row = row < n ? row : n - 1;     // clamp tail reads (stores guarded)
      if (AF32) {
        const float* Af = (const float*)Aptr;
        float4 f0 = *(const float4*)&Af[row * 128 + kt * 32 + hi * 8];
        float4 f1 = *(const float4*)&Af[row * 128 + kt * 32 + hi * 8 + 4];
        bf16x8 av;
        av[0] = (short)f2bf(f0.x); av[1] = (short)f2bf(f0.y);
        av[2] = (short)f2bf(f0.z); av[3] = (short)f2bf(f0.w);
        av[4] = (short)f2bf(f1.x); av[5] = (short)f2bf(f1.y);
        av[6] = (short)f2bf(f1.z); av[7] = (short)f2bf(f1.w);
        a[mi] = av;
      } else {
        const ushort* Ab = (const ushort*)Aptr;
        a[mi] = *(const bf16x8*)&Ab[row * 128 + kt * 32 + hi * 8];
      }
    }
#pragma unroll
    for (int mi = 0; mi < 4; ++mi)
#pragma unroll
      for (int nj = 0; nj < 4; ++nj)
        acc[mi][nj] = __builtin_amdgcn_mfma_f32_16x16x32_bf16(a[mi], b[nj], acc[mi][nj], 0, 0, 0);
  }

  // acc -> LDS (bias added)
#pragma unroll
  for (int nj = 0; nj < 4; ++nj) {
    int col = wv * 64 + nj * 16 + lr;
    float bb = (col < 128) ? bl[col] : br[col - 128];
#pragma unroll
    for (int mi = 0; mi < 4; ++mi)
#pragma unroll
      for (int v = 0; v < 4; ++v)
        tile[mi * 16 + hi * 4 + v][col] = f2bf(acc[mi][nj][v] + bb);
  }
  __syncthreads();

  // coalesced store: 8 chunks of 16B per thread
#pragma unroll
  for (int j = 0; j < 8; ++j) {
    int c = j * 256 + tid;          // 0..2047
    int rl = c >> 5;                // local row
    int colc = (c & 31) * 8;        // col chunk start
    int row = r0 + rl;
    if (row < n) {
      ushort* dstp = (colc < 128) ? &Xl[row * 128 + colc] : &Xr[row * 128 + (colc - 128)];
      *(ushort8v*)dstp = *(const ushort8v*)&tile[rl][colc];
    }
  }
}

// ---------------- CSR build ----------------
__global__ void zero_i32(int* p, int n) {
  int i = blockIdx.x * 256 + threadIdx.x;
  if (i < n) p[i] = 0;
}

__global__ void hist_kernel(const int* __restrict__ dst, int* __restrict__ deg) {
  int e = blockIdx.x * 256 + threadIdx.x;
  if (e < NE) atomicAdd(&deg[dst[e]], 1);
}

__global__ __launch_bounds__(256) void scan_a(const int* __restrict__ in,
                                              int* __restrict__ excl,
                                              int* __restrict__ bsum, int n) {
  int i = blockIdx.x * 256 + threadIdx.x;
  int v = (i < n) ? in[i] : 0;
  int lane = threadIdx.x & 63, wid = threadIdx.x >> 6;
  int incl = v;
#pragma unroll
  for (int off = 1; off < 64; off <<= 1) {
    int u = __shfl_up(incl, off);
    if (lane >= off) incl += u;
  }
  __shared__ int wsum[4];
  if (lane == 63) wsum[wid] = incl;
  __syncthreads();
  int wo = 0;
  for (int w = 0; w < wid; w++) wo += wsum[w];
  if (i < n) excl[i] = wo + incl - v;
  if (threadIdx.x == 255 && bsum) bsum[blockIdx.x] = wo + incl;
}

// finalize rowptr and init per-bucket cursors (bcur[b] = rowptr[b*128])
__global__ void scan_c(int* __restrict__ rowptr, const int* __restrict__ boff,
                       int* __restrict__ bcur, int n) {
  int i = blockIdx.x * 256 + threadIdx.x;
  if (i < n) {
    int v = rowptr[i] + boff[i >> 8];
    rowptr[i] = v;
    if ((i & 127) == 0) bcur[i >> 7] = v;
  } else if (i == n) {
    rowptr[n] = NE;
  }
}

// pass A: coarse-bucket edges (bucket = dst>>7); pairs packed dlocal<<17|src.
__global__ __launch_bounds__(256) void bucket_scatter(
    const int* __restrict__ src, const int* __restrict__ dst,
    int* __restrict__ bcur, unsigned int* __restrict__ pairs) {
  __shared__ int cnt[NBUK];
  __shared__ int base[NBUK];
  const int t = threadIdx.x;
  for (int i = t; i < NBUK; i += 256) cnt[i] = 0;
  __syncthreads();
  const int e0 = blockIdx.x * 4096;
#pragma unroll
  for (int j = 0; j < 16; ++j) {
    int e = e0 + j * 256 + t;
    if (e < NE) atomicAdd(&cnt[dst[e] >> 7], 1);
  }
  __syncthreads();
  for (int i = t; i < NBUK; i += 256) {
    int c = cnt[i];
    base[i] = c ? atomicAdd(&bcur[i], c) : 0;
    cnt[i] = 0;
  }
  __syncthreads();
#pragma unroll
  for (int j = 0; j < 16; ++j) {
    int e = e0 + j * 256 + t;
    if (e < NE) {
      int d = dst[e];
      int b = d >> 7;
      int r = atomicAdd(&cnt[b], 1);
      pairs[base[b] + r] = ((unsigned int)(d & 127) << 17) | (unsigned int)src[e];
    }
  }
}

// pass B: per-bucket fine sort with LDS cursors.
__global__ __launch_bounds__(256) void bucket_sort(
    const unsigned int* __restrict__ pairs, const int* __restrict__ rowptr,
    int* __restrict__ ssort) {
  __shared__ int cur[BNODES];
  const int b = blockIdx.x;
  const int n0 = b * BNODES;
  const int t = threadIdx.x;
  const int n1 = min(n0 + BNODES, NN);
  if (t < BNODES && n0 + t < NN) cur[t] = rowptr[n0 + t];
  __syncthreads();
  const int e0 = rowptr[n0];
  const int e1 = rowptr[n1];
  for (int e = e0 + t; e < e1; e += 256) {
    unsigned int p = pairs[e];
    int pos = atomicAdd(&cur[p >> 17], 1);
    ssort[pos] = (int)(p & 0x1FFFF);
  }
}

// ------- fused: logits + segment-softmax + aggregate + bias + ELU ---------
// 16 lanes/node x 8 channels/lane. Branchless logit, log2e folded.
template <int MODE>
__global__ __launch_bounds__(256) void gat_aggregate(
    const ushort* __restrict__ Xl, const ushort* __restrict__ Xr,
    const float* __restrict__ att, const int* __restrict__ ssort,
    const int* __restrict__ rowptr, const float* __restrict__ bias,
    ushort* __restrict__ outb,
    const float* __restrict__ Wl3, const float* __restrict__ Wr3,
    const float* __restrict__ bl3, const float* __restrict__ br3,
    float* __restrict__ xl3, float* __restrict__ xr3) {
  int slot = threadIdx.x >> 4;        // 16 nodes per block
  int l = threadIdx.x & 15;           // lane in node; head = l>>2
  int n = blockIdx.x * 16 + slot;
  if (n >= NN) return;
  int s0 = rowptr[n], s1 = rowptr[n + 1];
  ushort8v xru = *(const ushort8v*)&Xr[n * 128 + l * 8];
  const float L2E = 1.44269504f;
  float xr[8], a6[8], a4[8];
#pragma unroll
  for (int c = 0; c < 8; ++c) {
    xr[c] = bf2f(xru[c]);
    float a = att[l * 8 + c];
    a6[c] = 0.6f * L2E * a;
    a4[c] = 0.4f * L2E * a;
  }
  float den = 0.f;
  float A0[8], A1[8];
#pragma unroll
  for (int c = 0; c < 8; ++c) { A0[c] = 0.f; A1[c] = 0.f; }

  int i = s0;
  for (; i + 4 <= s1; i += 4) {
    int sa = ssort[i], sb = ssort[i + 1], sc = ssort[i + 2], sd = ssort[i + 3];
    ushort8v ua = *(const ushort8v*)&Xl[sa * 128 + l * 8];
    ushort8v ub = *(const ushort8v*)&Xl[sb * 128 + l * 8];
    ushort8v uc = *(const ushort8v*)&Xl[sc * 128 + l * 8];
    ushort8v ud = *(const ushort8v*)&Xl[sd * 128 + l * 8];
    float xa[8], xb[8], xc[8], xd[8];
    float pa = 0.f, pb = 0.f, pc = 0.f, pd = 0.f;
#pragma unroll
    for (int c = 0; c < 8; ++c) {
      float va;
      xa[c] = bf2f(ua[c]); va = xa[c] + xr[c];
      pa = fmaf(a6[c], va, pa); pa = fmaf(a4[c], fabsf(va), pa);
      xb[c] = bf2f(ub[c]); va = xb[c] + xr[c];
      pb = fmaf(a6[c], va, pb); pb = fmaf(a4[c], fabsf(va), pb);
      xc[c] = bf2f(uc[c]); va = xc[c] + xr[c];
      pc = fmaf(a6[c], va, pc); pc = fmaf(a4[c], fabsf(va), pc);
      xd[c] = bf2f(ud[c]); va = xd[c] + xr[c];
      pd = fmaf(a6[c], va, pd); pd = fmaf(a4[c], fabsf(va), pd);
    }
    pa += __shfl_xor(pa, 1); pa += __shfl_xor(pa, 2);
    pb += __shfl_xor(pb, 1); pb += __shfl_xor(pb, 2);
    pc += __shfl_xor(pc, 1); pc += __shfl_xor(pc, 2);
    pd += __shfl_xor(pd, 1); pd += __shfl_xor(pd, 2);
    float wa = exp2f(fminf(pa, 43.f));
    float wb = exp2f(fminf(pb, 43.f));
    float wc = exp2f(fminf(pc, 43.f));
    float wd = exp2f(fminf(pd, 43.f));
    den += (wa + wb) + (wc + wd);
#pragma unroll
    for (int c = 0; c < 8; ++c) {
      A0[c] = fmaf(wa, xa[c], A0[c]); A1[c] = fmaf(wb, xb[c], A1[c]);
      A0[c] = fmaf(wc, xc[c], A0[c]); A1[c] = fmaf(wd, xd[c], A1[c]);
    }
  }
  for (; i < s1; ++i) {
    int sa = ssort[i];
    ushort8v ua = *(const ushort8v*)&Xl[sa * 128 + l * 8];
    float xa[8], pa = 0.f;
#pragma unroll
    for (int c = 0; c < 8; ++c) {
      xa[c] = bf2f(ua[c]);
      float va = xa[c] + xr[c];
      pa = fmaf(a6[c], va, pa); pa = fmaf(a4[c], fabsf(va), pa);
    }
    pa += __shfl_xor(pa, 1); pa += __shfl_xor(pa, 2);
    float wa = exp2f(fminf(pa, 43.f));
    den += wa;
#pragma unroll
    for (int c = 0; c < 8; ++c) A0[c] = fmaf(wa, xa[c], A0[c]);
  }
  float inv = 1.f / (den + 1e-16f);
  float o[8];
#pragma unroll
  for (int c = 0; c < 8; ++c) {
    o[c] = (A0[c] + A1[c]) * inv + bias[l * 8 + c];
    o[c] = o[c] > 0.f ? o[c] : __expf(o[c]) - 1.f;
  }
  if (MODE == 0) {
    ushort8v ub;
#pragma unroll
    for (int c = 0; c < 8; ++c) ub[c] = f2bf(o[c]);
    *(ushort8v*)&outb[n * 128 + l * 8] = ub;
  } else {
    float sl = 0.f, sr = 0.f;
#pragma unroll
    for (int c = 0; c < 8; ++c) {
      sl = fmaf(o[c], Wl3[l * 8 + c], sl);
      sr = fmaf(o[c], Wr3[l * 8 + c], sr);
    }
#pragma unroll
    for (int off = 1; off <= 8; off <<= 1) {
      sl += __shfl_xor(sl, off);
      sr += __shfl_xor(sr, off);
    }
    if (l == 0) {
      xl3[n] = sl + bl3[0];
      xr3[n] = sr + br3[0];
    }
  }
}

// fused layer-3 edge phase: per-node wave, no-max softmax, wave merge
__global__ __launch_bounds__(256) void aggregate3_fused(
    const float* __restrict__ xl3, const float* __restrict__ xr3,
    const float* __restrict__ att, const int* __restrict__ ssort,
    const int* __restrict__ rowptr, const float* __restrict__ bias,
    float* __restrict__ out, int nn) {
  int wid = threadIdx.x >> 6, lane = threadIdx.x & 63;
  int n = blockIdx.x * 4 + wid;
  if (n >= nn) return;
  int s0 = rowptr[n], s1 = rowptr[n + 1];
  float xr = xr3[n];
  const float L2E = 1.44269504f;
  float s6 = 0.6f * L2E * att[0];
  float s4 = 0.4f * L2E * att[0];
  float den = 0.f, acc = 0.f;
  for (int i = s0 + lane; i < s1; i += 64) {
    float xl = xl3[ssort[i]];
    float v = xl + xr;
    float p = fmaf(s6, v, s4 * fabsf(v));
    float w = exp2f(fminf(p, 43.f));
    den += w;
    acc += w * xl;
  }
#pragma unroll
  for (int off = 32; off; off >>= 1) {
    den += __shfl_xor(den, off);
    acc += __shfl_xor(acc, off);
  }
  if (lane == 0) {
    float o = acc / (den + 1e-16f) + bias[0];
    out[n] = 1.f / (1.f + __expf(-o));
  }
}

extern "C" void kernel_launch(void* const* d_in, const int* in_sizes, int n_in,
                              void* d_out, int out_size, void* d_ws, size_t ws_size,
                              hipStream_t stream) {
  const float* x = (const float*)d_in[0];
  const int* ei = (const int*)d_in[1];
  const int* src = ei;
  const int* dst = ei + NE;
  const float* W_l1 = (const float*)d_in[2];
  const float* b_l1 = (const float*)d_in[3];
  const float* W_r1 = (const float*)d_in[4];
  const float* b_r1 = (const float*)d_in[5];
  const float* att1 = (const float*)d_in[6];
  const float* bias1 = (const float*)d_in[7];
  const float* W_l2 = (const float*)d_in[8];
  const float* b_l2 = (const float*)d_in[9];
  const float* W_r2 = (const float*)d_in[10];
  const float* b_r2 = (const float*)d_in[11];
  const float* att2 = (const float*)d_in[12];
  const float* bias2 = (const float*)d_in[13];
  const float* W_l3 = (const float*)d_in[14];
  const float* b_l3 = (const float*)d_in[15];
  const float* W_r3 = (const float*)d_in[16];
  const float* b_r3 = (const float*)d_in[17];
  const float* att3 = (const float*)d_in[18];
  const float* bias3 = (const float*)d_in[19];
  float* out = (float*)d_out;

  ushort* xbb = (ushort*)d_ws;           // NN*128 bf16 (layer-2 gemm A input)
  ushort* xl_b = xbb + NN * 128;         // NN*128 bf16
  ushort* xr_b = xl_b + NN * 128;        // NN*128 bf16
  ushort* bpack1 = xr_b + NN * 128;      // 32768 bf16
  ushort* bpack2 = bpack1 + 32768;       // 32768 bf16
  int* deg = (int*)(bpack2 + 32768);     // NN
  int* rowptr = deg + NN;                // NN+1
  int* bcur = rowptr + NN + 1;           // NBUK
  int* bsum = bcur + NBUK;               // 256
  int* boff = bsum + 256;                // 256
  int* ssort = boff + 256;               // NE
  unsigned int* pairs = (unsigned int*)(ssort + NE);  // NE packed
  float* xl3 = (float*)(pairs + NE);     // NN
  float* xr3 = xl3 + NN;                 // NN

  const int NB_N = (NN + 255) / 256;     // 196
  const int NB_E = (NE + 255) / 256;     // 3125
  const int NB_G = (NN + 63) / 64;       // 782
  const int NB_A = (NN + 15) / 16;       // 3125
  const int NB_W4 = (NN + 3) / 4;        // 12500
  const int NB_BK = (NE + 4095) / 4096;  // 196

  // ---- CSR build (bucketed counting sort, separate kernels) ----
  zero_i32<<<NB_N, 256, 0, stream>>>(deg, NN);
  hist_kernel<<<NB_E, 256, 0, stream>>>(dst, deg);
  scan_a<<<NB_N, 256, 0, stream>>>(deg, rowptr, bsum, NN);
  scan_a<<<1, 256, 0, stream>>>(bsum, boff, (int*)nullptr, NB_N);
  scan_c<<<NB_N + 1, 256, 0, stream>>>(rowptr, boff, bcur, NN);
  bucket_scatter<<<NB_BK, 256, 0, stream>>>(src, dst, bcur, pairs);
  bucket_sort<<<NBUK, 256, 0, stream>>>(pairs, rowptr, ssort);

  // ---- weight packing (both layers, one launch) ----
  pack_w_both<<<32, 256, 0, stream>>>(W_l1, W_r1, W_l2, W_r2, bpack1, bpack2);

  // ---- layer 1 (A = fp32 x, converted in-register) ----
  gemm_mfma<1><<<NB_G, 256, 0, stream>>>(x, bpack1, b_l1, b_r1, xl_b, xr_b, NN);
  gat_aggregate<0><<<NB_A, 256, 0, stream>>>(xl_b, xr_b, att1, ssort, rowptr, bias1,
                                             xbb, nullptr, nullptr, nullptr, nullptr,
                                             nullptr, nullptr);

  // ---- layer 2 (+ fused layer-3 GEMV epilogue) ----
  gemm_mfma<0><<<NB_G, 256, 0, stream>>>(xbb, bpack2, b_l2, b_r2, xl_b, xr_b, NN);
  gat_aggregate<1><<<NB_A, 256, 0, stream>>>(xl_b, xr_b, att2, ssort, rowptr, bias2,
                                             nullptr, W_l3, W_r3, b_l3, b_r3,
                                             xl3, xr3);

  // ---- layer 3 edge phase ----
  aggregate3_fused<<<NB_W4, 256, 0, stream>>>(xl3, xr3, att3, ssort, rowptr, bias3, out, NN);
}